// Round 2
// baseline (965.855 us; speedup 1.0000x reference)
//
#include <hip/hip_runtime.h>
#include <hip/hip_cooperative_groups.h>

namespace cg = cooperative_groups;

#define F 128
#define ROWS2 32
#define SCAN_TILE 1024

// ============================================================================
// Cooperative CSR-build kernel: replaces prep + hist + scan1 + scan2 + scan3 +
// place (6 launches + 5 gaps -> 1 launch). Offsets are kept TILE-LOCAL;
// consumers add blockSums[v >> 10] (tile base, L1-hot) on the fly, which
// eliminates the scan3 full-N pass entirely.
// ============================================================================
__global__ __launch_bounds__(256) void build_csr_kernel(
        const float* __restrict__ W, float* __restrict__ wT,
        const int* __restrict__ src, const int* __restrict__ dst,
        int* __restrict__ counts, int* __restrict__ offsets,
        int* __restrict__ cursor, int* __restrict__ blockSums,
        int* __restrict__ ssrc, int N, int E, int NB) {
    cg::grid_group grid = cg::this_grid();
    __shared__ int lds[256];
    const int tid = threadIdx.x;
    const int gid = blockIdx.x * 256 + tid;
    const int gsize = gridDim.x * 256;

    // ---- phase Z: zero counts + transpose W (wT[k*F+o] = W[o*F+k]) ----
    for (int i = gid; i < N; i += gsize) counts[i] = 0;
    if (gid < F * F) {
        int o = gid >> 7, k = gid & 127;
        wT[k * F + o] = W[gid];
    }
    grid.sync();

    // ---- phase H: histogram of dst (int4-vectorized) ----
    const int E4 = E >> 2;
    for (int i = gid; i < E4; i += gsize) {
        const int4 d = ((const int4*)dst)[i];
        atomicAdd(&counts[d.x], 1);
        atomicAdd(&counts[d.y], 1);
        atomicAdd(&counts[d.z], 1);
        atomicAdd(&counts[d.w], 1);
    }
    for (int e = (E4 << 2) + gid; e < E; e += gsize) atomicAdd(&counts[dst[e]], 1);
    grid.sync();

    // ---- phase S1: per-tile (1024) exclusive scan -> LOCAL offsets + tile sums
    if (blockIdx.x < NB) {
        const int i0 = blockIdx.x * SCAN_TILE + tid * 4;
        int v[4];
        int s = 0;
#pragma unroll
        for (int j = 0; j < 4; ++j) {
            int i = i0 + j;
            v[j] = (i < N) ? counts[i] : 0;
            s += v[j];
        }
        lds[tid] = s;
        __syncthreads();
        for (int off = 1; off < 256; off <<= 1) {
            int t = (tid >= off) ? lds[tid - off] : 0;
            __syncthreads();
            lds[tid] += t;
            __syncthreads();
        }
        int excl = lds[tid] - s;
#pragma unroll
        for (int j = 0; j < 4; ++j) {
            int i = i0 + j;
            if (i < N) {
                offsets[i] = excl;   // tile-local
                cursor[i] = excl;    // tile-local running cursor for place
            } else if (i == N) {
                offsets[N] = excl;   // local prefix at N (within its tile)
            }
            excl += v[j];
        }
        if (tid == 255) blockSums[blockIdx.x] = lds[255];  // tile sum
    }
    grid.sync();

    // ---- phase S2: block 0 scans tile sums -> blockSums becomes tile BASE ----
    if (blockIdx.x == 0) {
        int s = (tid < NB) ? blockSums[tid] : 0;
        lds[tid] = s;
        __syncthreads();
        for (int off = 1; off < 256; off <<= 1) {
            int t = (tid >= off) ? lds[tid - off] : 0;
            __syncthreads();
            lds[tid] += t;
            __syncthreads();
        }
        if (tid < NB) blockSums[tid] = lds[tid] - s;  // exclusive base per tile
    }
    grid.sync();

    // ---- phase P: place edges (global pos = local cursor + tile base) ----
    for (int i = gid; i < E4; i += gsize) {
        const int4 d = ((const int4*)dst)[i];
        const int4 sv = ((const int4*)src)[i];
        ssrc[atomicAdd(&cursor[d.x], 1) + blockSums[d.x >> 10]] = sv.x;
        ssrc[atomicAdd(&cursor[d.y], 1) + blockSums[d.y >> 10]] = sv.y;
        ssrc[atomicAdd(&cursor[d.z], 1) + blockSums[d.z >> 10]] = sv.z;
        ssrc[atomicAdd(&cursor[d.w], 1) + blockSums[d.w >> 10]] = sv.w;
    }
    for (int e = (E4 << 2) + gid; e < E; e += gsize) {
        int d = dst[e];
        ssrc[atomicAdd(&cursor[d], 1) + blockSums[d >> 10]] = src[e];
    }
}

// ============================================================================
// Non-cooperative fallback chain (used only if cooperative launch unavailable)
// ============================================================================
__global__ void prep2_kernel(const float* __restrict__ W, float* __restrict__ wT,
                             int* __restrict__ counts, int N) {
    int i = blockIdx.x * 256 + threadIdx.x;
    if (i < F * F) {
        int o = i >> 7, k = i & 127;
        wT[k * F + o] = W[i];
    }
    if (i < N) counts[i] = 0;
}

__global__ void hist_kernel(const int* __restrict__ dst, int* __restrict__ counts, int E) {
    int e = blockIdx.x * blockDim.x + threadIdx.x;
    if (e < E) atomicAdd(&counts[dst[e]], 1);
}

__global__ __launch_bounds__(256) void scan1_kernel(const int* __restrict__ counts,
                                                    int* __restrict__ offsets,
                                                    int* __restrict__ cursor,
                                                    int* __restrict__ blockSums, int N) {
    __shared__ int lds[256];
    const int tid = threadIdx.x;
    const int i0 = blockIdx.x * SCAN_TILE + tid * 4;
    int v[4];
    int s = 0;
#pragma unroll
    for (int j = 0; j < 4; ++j) {
        int i = i0 + j;
        v[j] = (i < N) ? counts[i] : 0;
        s += v[j];
    }
    lds[tid] = s;
    __syncthreads();
    for (int off = 1; off < 256; off <<= 1) {
        int t = (tid >= off) ? lds[tid - off] : 0;
        __syncthreads();
        lds[tid] += t;
        __syncthreads();
    }
    int excl = lds[tid] - s;
#pragma unroll
    for (int j = 0; j < 4; ++j) {
        int i = i0 + j;
        if (i < N) {
            offsets[i] = excl;
            cursor[i] = excl;
        } else if (i == N) {
            offsets[N] = excl;
        }
        excl += v[j];
    }
    if (tid == 255) blockSums[blockIdx.x] = lds[255];
}

__global__ __launch_bounds__(256) void scan2_kernel(int* __restrict__ blockSums, int NB) {
    __shared__ int lds[256];
    const int tid = threadIdx.x;
    int s = (tid < NB) ? blockSums[tid] : 0;
    lds[tid] = s;
    __syncthreads();
    for (int off = 1; off < 256; off <<= 1) {
        int t = (tid >= off) ? lds[tid - off] : 0;
        __syncthreads();
        lds[tid] += t;
        __syncthreads();
    }
    if (tid < NB) blockSums[tid] = lds[tid] - s;
}

__global__ void place_kernel(const int* __restrict__ src, const int* __restrict__ dst,
                             int* __restrict__ cursor, const int* __restrict__ base,
                             int* __restrict__ ssrc, int E) {
    int e = blockIdx.x * blockDim.x + threadIdx.x;
    if (e < E) {
        int d = dst[e];
        int pos = atomicAdd(&cursor[d], 1) + base[d >> 10];
        ssrc[pos] = src[e];
    }
}

// ============================================================================
// Round-0-proven aggregation: one wave per node; half-wave pairs process
// alternate edges with float4 loads, combined via cross-half shuffle.
// Only change vs round 0: offsets are tile-local, add base[v>>10].
// ============================================================================
__global__ __launch_bounds__(256) void agg_kernel(const float* __restrict__ feat,
                                                  const int* __restrict__ ssrc,
                                                  const int* __restrict__ offs,
                                                  const int* __restrict__ base,
                                                  float* __restrict__ out, int N) {
    const int gwave = (blockIdx.x * blockDim.x + threadIdx.x) >> 6;
    const int lane = threadIdx.x & 63;
    const int half = lane >> 5;   // which edge of each pair
    const int q = lane & 31;      // float4 index within the 128-float row
    const int nwaves = (gridDim.x * blockDim.x) >> 6;
    const float4* feat4 = (const float4*)feat;
    for (int v = gwave; v < N; v += nwaves) {
        const int s0 = offs[v] + base[v >> 10];
        const int s1 = offs[v + 1] + base[(v + 1) >> 10];
        float ax = 0.f, ay = 0.f, az = 0.f, aw = 0.f;
        int e = s0 + half;
        for (; e + 6 < s1; e += 8) {   // 4 edges per half = 8 edges/wave/iter
            int i0 = ssrc[e], i1 = ssrc[e + 2], i2 = ssrc[e + 4], i3 = ssrc[e + 6];
            const float4 f0 = feat4[(size_t)i0 * 32 + q];
            const float4 f1 = feat4[(size_t)i1 * 32 + q];
            const float4 f2 = feat4[(size_t)i2 * 32 + q];
            const float4 f3 = feat4[(size_t)i3 * 32 + q];
            ax += (f0.x + f1.x) + (f2.x + f3.x);
            ay += (f0.y + f1.y) + (f2.y + f3.y);
            az += (f0.z + f1.z) + (f2.z + f3.z);
            aw += (f0.w + f1.w) + (f2.w + f3.w);
        }
        for (; e < s1; e += 2) {
            const float4 f0 = feat4[(size_t)ssrc[e] * 32 + q];
            ax += f0.x; ay += f0.y; az += f0.z; aw += f0.w;
        }
        ax += __shfl_xor(ax, 32);
        ay += __shfl_xor(ay, 32);
        az += __shfl_xor(az, 32);
        aw += __shfl_xor(aw, 32);
        if (half == 0) {
            float4 r;
            r.x = ax; r.y = ay; r.z = az; r.w = aw;
            ((float4*)(out + (size_t)v * F))[q] = r;
        }
    }
}

// In-place h = relu(agg @ W^T + b), reading pre-transposed wT (round-0 proven).
__global__ __launch_bounds__(256) void linear_relu_kernel(
        float* __restrict__ h, const float* __restrict__ wT,
        const float* __restrict__ b, int N) {
    __shared__ __align__(16) float sA[ROWS2][132];
    const int tid = threadIdx.x;
    const int row0 = blockIdx.x * ROWS2;

    for (int i = tid; i < ROWS2 * 32; i += 256) {
        int r = i >> 5, q = i & 31;
        int gr = row0 + r;
        float4 v = make_float4(0.f, 0.f, 0.f, 0.f);
        if (gr < N) v = ((const float4*)(h + (size_t)gr * F))[q];
        *((float4*)&sA[r][q << 2]) = v;
    }
    __syncthreads();

    const int tr = tid >> 5;   // 0..7 -> rows tr*4 .. tr*4+3
    const int tc = tid & 31;   // cols tc*4 .. tc*4+3
    float acc[4][4];
#pragma unroll
    for (int i = 0; i < 4; ++i)
#pragma unroll
        for (int j = 0; j < 4; ++j) acc[i][j] = 0.f;

    const float4* wT4 = (const float4*)wT;
    for (int k = 0; k < F; k += 4) {
        const float4 w0 = wT4[(k + 0) * 32 + tc];
        const float4 w1 = wT4[(k + 1) * 32 + tc];
        const float4 w2 = wT4[(k + 2) * 32 + tc];
        const float4 w3 = wT4[(k + 3) * 32 + tc];
#pragma unroll
        for (int i = 0; i < 4; ++i) {
            const float4 a = *(const float4*)&sA[tr * 4 + i][k];  // broadcast
            acc[i][0] += a.x * w0.x + a.y * w1.x + a.z * w2.x + a.w * w3.x;
            acc[i][1] += a.x * w0.y + a.y * w1.y + a.z * w2.y + a.w * w3.y;
            acc[i][2] += a.x * w0.z + a.y * w1.z + a.z * w2.z + a.w * w3.z;
            acc[i][3] += a.x * w0.w + a.y * w1.w + a.z * w2.w + a.w * w3.w;
        }
    }

    const float4 bias = ((const float4*)b)[tc];
#pragma unroll
    for (int i = 0; i < 4; ++i) {
        int gr = row0 + tr * 4 + i;
        if (gr < N) {
            float4 o;
            o.x = fmaxf(acc[i][0] + bias.x, 0.f);
            o.y = fmaxf(acc[i][1] + bias.y, 0.f);
            o.z = fmaxf(acc[i][2] + bias.z, 0.f);
            o.w = fmaxf(acc[i][3] + bias.w, 0.f);
            ((float4*)(h + (size_t)gr * F))[tc] = o;
        }
    }
}

// ---------------- ws-too-small fallback path (R1-proven) ----------------
__global__ void zero_f4_kernel(float4* __restrict__ out, int n4) {
    int i = blockIdx.x * blockDim.x + threadIdx.x;
    if (i < n4) out[i] = make_float4(0.f, 0.f, 0.f, 0.f);
}

__global__ void scatter_atomic_kernel(const float* __restrict__ feat,
                                      const int* __restrict__ src,
                                      const int* __restrict__ dst,
                                      float* __restrict__ agg, int E) {
    int gid = blockIdx.x * blockDim.x + threadIdx.x;
    int e = gid >> 5;
    if (e >= E) return;
    int q = gid & 31;
    int s = src[e];
    int d = dst[e];
    const float4 v = ((const float4*)(feat + (size_t)s * F))[q];
    float* o = agg + (size_t)d * F + (q << 2);
    atomicAdd(o + 0, v.x);
    atomicAdd(o + 1, v.y);
    atomicAdd(o + 2, v.z);
    atomicAdd(o + 3, v.w);
}

__global__ __launch_bounds__(256) void linear_relu_w_kernel(
        float* __restrict__ h, const float* __restrict__ W,
        const float* __restrict__ b, int N) {
    __shared__ __align__(16) float sA[64][132];
    const int tid = threadIdx.x;
    const int row0 = blockIdx.x * 64;

    for (int i = tid; i < 64 * 32; i += 256) {
        int r = i >> 5, q = i & 31;
        int gr = row0 + r;
        float4 v = make_float4(0.f, 0.f, 0.f, 0.f);
        if (gr < N) v = ((const float4*)(h + (size_t)gr * F))[q];
        *((float4*)&sA[r][q << 2]) = v;
    }
    __syncthreads();

    const int tr = tid >> 5;
    const int tc = tid & 31;
    float acc[8][4];
#pragma unroll
    for (int i = 0; i < 8; ++i)
#pragma unroll
        for (int j = 0; j < 4; ++j) acc[i][j] = 0.f;

    const float* Wr0 = W + (size_t)(tc * 4 + 0) * F;
    const float* Wr1 = W + (size_t)(tc * 4 + 1) * F;
    const float* Wr2 = W + (size_t)(tc * 4 + 2) * F;
    const float* Wr3 = W + (size_t)(tc * 4 + 3) * F;

    for (int k = 0; k < F; k += 4) {
        const float4 w0 = *(const float4*)&Wr0[k];
        const float4 w1 = *(const float4*)&Wr1[k];
        const float4 w2 = *(const float4*)&Wr2[k];
        const float4 w3 = *(const float4*)&Wr3[k];
#pragma unroll
        for (int i = 0; i < 8; ++i) {
            const float4 a = *(const float4*)&sA[tr * 8 + i][k];
            acc[i][0] += a.x * w0.x + a.y * w0.y + a.z * w0.z + a.w * w0.w;
            acc[i][1] += a.x * w1.x + a.y * w1.y + a.z * w1.z + a.w * w1.w;
            acc[i][2] += a.x * w2.x + a.y * w2.y + a.z * w2.z + a.w * w2.w;
            acc[i][3] += a.x * w3.x + a.y * w3.y + a.z * w3.z + a.w * w3.w;
        }
    }

    const float4 bias = ((const float4*)b)[tc];
#pragma unroll
    for (int i = 0; i < 8; ++i) {
        int gr = row0 + tr * 8 + i;
        if (gr < N) {
            float4 o;
            o.x = fmaxf(acc[i][0] + bias.x, 0.f);
            o.y = fmaxf(acc[i][1] + bias.y, 0.f);
            o.z = fmaxf(acc[i][2] + bias.z, 0.f);
            o.w = fmaxf(acc[i][3] + bias.w, 0.f);
            ((float4*)(h + (size_t)gr * F))[tc] = o;
        }
    }
}

extern "C" void kernel_launch(void* const* d_in, const int* in_sizes, int n_in,
                              void* d_out, int out_size, void* d_ws, size_t ws_size,
                              hipStream_t stream) {
    const float* feat = (const float*)d_in[0];
    const int*   src  = (const int*)d_in[1];
    const int*   dst  = (const int*)d_in[2];
    const float* W    = (const float*)d_in[3];
    const float* b    = (const float*)d_in[4];
    float* out = (float*)d_out;

    const int N = in_sizes[0] / F;   // 50000
    const int E = in_sizes[1];       // 800000
    const int NB = (N + SCAN_TILE - 1) / SCAN_TILE;  // 49 (<=256)

    // ws layout (4B elems): counts[N] | offsets[N+1] | cursor[N] | blockSums[256]
    //                     | ssrc[E] | pad | wT[128*128] (16B-aligned)
    const size_t ints_before = (size_t)N + (N + 1) + N + 256 + E;
    const size_t wT_off = (ints_before + 3) & ~(size_t)3;
    const size_t ws_needed = (wT_off + (size_t)F * F) * sizeof(int);

    if (ws_size >= ws_needed && NB <= 256) {
        int* counts    = (int*)d_ws;
        int* offsets   = counts + N;
        int* cursor    = offsets + (N + 1);
        int* blockSums = cursor + N;
        int* ssrc      = blockSums + 256;
        float* wT      = (float*)d_ws + wT_off;

        // Cached cooperative-launch capability: max co-resident grid for the
        // CSR kernel (guarantees grid.sync can't deadlock).
        static int coop_grid = -1;
        if (coop_grid < 0) {
            int nb = 0;
            hipError_t e1 = hipOccupancyMaxActiveBlocksPerMultiprocessor(
                &nb, build_csr_kernel, 256, 0);
            int ncu = 0;
            hipDeviceProp_t prop;
            int dev = 0;
            hipGetDevice(&dev);
            if (hipGetDeviceProperties(&prop, dev) == hipSuccess)
                ncu = prop.multiProcessorCount;
            int g = (e1 == hipSuccess && nb > 0 && ncu > 0) ? nb * ncu : 0;
            if (g > 2048) g = 2048;
            coop_grid = g;
        }

        int Nk = N, Ek = E, NBk = NB;
        bool csr_done = false;
        if (coop_grid >= NB) {
            void* args[] = {(void*)&W, (void*)&wT, (void*)&src, (void*)&dst,
                            (void*)&counts, (void*)&offsets, (void*)&cursor,
                            (void*)&blockSums, (void*)&ssrc,
                            (void*)&Nk, (void*)&Ek, (void*)&NBk};
            if (hipLaunchCooperativeKernel((const void*)build_csr_kernel,
                                           dim3(coop_grid), dim3(256),
                                           args, 0, stream) == hipSuccess) {
                csr_done = true;
            } else {
                coop_grid = 0;  // don't retry the cooperative path
            }
        }
        if (!csr_done) {
            prep2_kernel<<<(N + 255) / 256, 256, 0, stream>>>(W, wT, counts, N);
            hist_kernel<<<(E + 255) / 256, 256, 0, stream>>>(dst, counts, E);
            scan1_kernel<<<NB, 256, 0, stream>>>(counts, offsets, cursor, blockSums, N);
            scan2_kernel<<<1, 256, 0, stream>>>(blockSums, NB);
            place_kernel<<<(E + 255) / 256, 256, 0, stream>>>(src, dst, cursor, blockSums, ssrc, E);
        }

        agg_kernel<<<2048, 256, 0, stream>>>(feat, ssrc, offsets, blockSums, out, N);
        linear_relu_kernel<<<(N + ROWS2 - 1) / ROWS2, 256, 0, stream>>>(out, wT, b, N);
    } else {
        const int n4 = N * (F / 4);
        zero_f4_kernel<<<(n4 + 255) / 256, 256, 0, stream>>>((float4*)out, n4);
        const int sthreads = E * 32;
        scatter_atomic_kernel<<<(sthreads + 255) / 256, 256, 0, stream>>>(feat, src, dst, out, E);
        linear_relu_w_kernel<<<(N + 63) / 64, 256, 0, stream>>>(out, W, b, N);
    }
}

// Round 3
// 245.617 us; speedup vs baseline: 3.9324x; 3.9324x over previous
//
#include <hip/hip_runtime.h>
#include <hip/hip_fp16.h>

#define F 128
#define ROWS2 32
#define SCAN_TILE 1024

// ============================================================================
// prep (main path): feat fp32 -> fp16 (halves gather bandwidth), zero counts,
// transpose W. One launch.
// ============================================================================
__global__ __launch_bounds__(256) void prep_full_kernel(
        const float* __restrict__ feat, unsigned int* __restrict__ featH,
        const float* __restrict__ W, float* __restrict__ wT,
        int* __restrict__ counts, int N, int NF4) {
    int i = blockIdx.x * 256 + threadIdx.x;
    if (i < NF4) {
        const float4 v = ((const float4*)feat)[i];
        union { __half2 h; unsigned int u; } a, b;
        a.h = __floats2half2_rn(v.x, v.y);
        b.h = __floats2half2_rn(v.z, v.w);
        ((uint2*)featH)[i] = make_uint2(a.u, b.u);
    }
    if (i < F * F) {
        int o = i >> 7, k = i & 127;
        wT[k * F + o] = W[i];
    }
    if (i < N) counts[i] = 0;
}

// prep (mid path, no fp16): zero counts + transpose W.
__global__ void prep2_kernel(const float* __restrict__ W, float* __restrict__ wT,
                             int* __restrict__ counts, int N) {
    int i = blockIdx.x * 256 + threadIdx.x;
    if (i < F * F) {
        int o = i >> 7, k = i & 127;
        wT[k * F + o] = W[i];
    }
    if (i < N) counts[i] = 0;
}

__global__ void hist_kernel(const int* __restrict__ dst, int* __restrict__ counts, int E) {
    int e = blockIdx.x * blockDim.x + threadIdx.x;
    if (e < E) atomicAdd(&counts[dst[e]], 1);
}

// scan1: per-tile (1024) exclusive scan -> TILE-LOCAL offsets + cursor + tile sums.
__global__ __launch_bounds__(256) void scan1_kernel(const int* __restrict__ counts,
                                                    int* __restrict__ offsets,
                                                    int* __restrict__ cursor,
                                                    int* __restrict__ blockSums, int N) {
    __shared__ int lds[256];
    const int tid = threadIdx.x;
    const int i0 = blockIdx.x * SCAN_TILE + tid * 4;
    int v[4];
    int s = 0;
#pragma unroll
    for (int j = 0; j < 4; ++j) {
        int i = i0 + j;
        v[j] = (i < N) ? counts[i] : 0;
        s += v[j];
    }
    lds[tid] = s;
    __syncthreads();
    for (int off = 1; off < 256; off <<= 1) {
        int t = (tid >= off) ? lds[tid - off] : 0;
        __syncthreads();
        lds[tid] += t;
        __syncthreads();
    }
    int excl = lds[tid] - s;
#pragma unroll
    for (int j = 0; j < 4; ++j) {
        int i = i0 + j;
        if (i < N) {
            offsets[i] = excl;   // tile-local
            cursor[i] = excl;    // tile-local running cursor for place
        } else if (i == N) {
            offsets[N] = excl;   // local prefix at N within its tile
        }
        excl += v[j];
    }
    if (tid == 255) blockSums[blockIdx.x] = lds[255];  // tile sum
}

// scan2: scan tile sums -> blockSums becomes tile BASE. Guards for N%1024==0.
__global__ __launch_bounds__(256) void scan2_kernel(int* __restrict__ blockSums,
                                                    int* __restrict__ offsets,
                                                    int NB, int N) {
    __shared__ int lds[256];
    const int tid = threadIdx.x;
    int s = (tid < NB) ? blockSums[tid] : 0;
    lds[tid] = s;
    __syncthreads();
    for (int off = 1; off < 256; off <<= 1) {
        int t = (tid >= off) ? lds[tid - off] : 0;
        __syncthreads();
        lds[tid] += t;
        __syncthreads();
    }
    if (tid < NB) blockSums[tid] = lds[tid] - s;        // exclusive base per tile
    if (tid == NB && NB < 256) blockSums[NB] = lds[255];  // total (for N%1024==0)
    if (tid == 0 && (N & (SCAN_TILE - 1)) == 0) offsets[N] = 0;
}

__global__ void place_kernel(const int* __restrict__ src, const int* __restrict__ dst,
                             int* __restrict__ cursor, const int* __restrict__ base,
                             int* __restrict__ ssrc, int E) {
    int e = blockIdx.x * blockDim.x + threadIdx.x;
    if (e < E) {
        int d = dst[e];
        int pos = atomicAdd(&cursor[d], 1) + base[d >> 10];
        ssrc[pos] = src[e];
    }
}

// ============================================================================
// fp16 gather-aggregate (main path). Wave of 64 = 4 edge-groups x 16 lanes.
// Each lane loads one uint4 (8 fp16 = 256B/row across 16 lanes), accumulates
// 8 fp32 columns; cross-group reduce via shfl_xor(16,32); lanes 0-15 write the
// 512B fp32 output row. Halves both logical gather bytes and L2-miss traffic
// vs the fp32 version (was 57.6us @ 175MB FETCH).
// ============================================================================
__global__ __launch_bounds__(256) void agg16_kernel(
        const uint4* __restrict__ fH,    // N x 16 uint4 rows (128 fp16)
        const int* __restrict__ ssrc,
        const int* __restrict__ offs,
        const int* __restrict__ base,
        float* __restrict__ out, int N) {
    const int gwave = (blockIdx.x * blockDim.x + threadIdx.x) >> 6;
    const int lane = threadIdx.x & 63;
    const int g = lane >> 4;      // edge slot 0..3
    const int q = lane & 15;      // 16B chunk within the 256B row
    const int nwaves = (gridDim.x * blockDim.x) >> 6;

    for (int v = gwave; v < N; v += nwaves) {
        const int s0 = offs[v] + base[v >> 10];
        const int s1 = offs[v + 1] + base[(v + 1) >> 10];
        float a[8];
#pragma unroll
        for (int j = 0; j < 8; ++j) a[j] = 0.f;

        int e = s0 + g;
        for (; e + 4 < s1; e += 8) {   // 8 edges per wave-iter (2 per group)
            const int i0 = ssrc[e], i1 = ssrc[e + 4];
            const uint4 u0 = fH[(size_t)i0 * 16 + q];
            const uint4 u1 = fH[(size_t)i1 * 16 + q];
            {
                union { unsigned int u; __half2 h; } c0, c1, c2, c3;
                c0.u = u0.x; c1.u = u0.y; c2.u = u0.z; c3.u = u0.w;
                const float2 f0 = __half22float2(c0.h);
                const float2 f1 = __half22float2(c1.h);
                const float2 f2 = __half22float2(c2.h);
                const float2 f3 = __half22float2(c3.h);
                a[0] += f0.x; a[1] += f0.y; a[2] += f1.x; a[3] += f1.y;
                a[4] += f2.x; a[5] += f2.y; a[6] += f3.x; a[7] += f3.y;
            }
            {
                union { unsigned int u; __half2 h; } c0, c1, c2, c3;
                c0.u = u1.x; c1.u = u1.y; c2.u = u1.z; c3.u = u1.w;
                const float2 f0 = __half22float2(c0.h);
                const float2 f1 = __half22float2(c1.h);
                const float2 f2 = __half22float2(c2.h);
                const float2 f3 = __half22float2(c3.h);
                a[0] += f0.x; a[1] += f0.y; a[2] += f1.x; a[3] += f1.y;
                a[4] += f2.x; a[5] += f2.y; a[6] += f3.x; a[7] += f3.y;
            }
        }
        for (; e < s1; e += 4) {       // tail: up to 7 edges, group-strided
            const uint4 u0 = fH[(size_t)ssrc[e] * 16 + q];
            union { unsigned int u; __half2 h; } c0, c1, c2, c3;
            c0.u = u0.x; c1.u = u0.y; c2.u = u0.z; c3.u = u0.w;
            const float2 f0 = __half22float2(c0.h);
            const float2 f1 = __half22float2(c1.h);
            const float2 f2 = __half22float2(c2.h);
            const float2 f3 = __half22float2(c3.h);
            a[0] += f0.x; a[1] += f0.y; a[2] += f1.x; a[3] += f1.y;
            a[4] += f2.x; a[5] += f2.y; a[6] += f3.x; a[7] += f3.y;
        }

#pragma unroll
        for (int j = 0; j < 8; ++j) {
            a[j] += __shfl_xor(a[j], 16);
            a[j] += __shfl_xor(a[j], 32);
        }
        if (g == 0) {
            float4* orow = (float4*)(out + (size_t)v * F);
            float4 r0, r1;
            r0.x = a[0]; r0.y = a[1]; r0.z = a[2]; r0.w = a[3];
            r1.x = a[4]; r1.y = a[5]; r1.z = a[6]; r1.w = a[7];
            orow[q * 2] = r0;
            orow[q * 2 + 1] = r1;
        }
    }
}

// fp32 gather-aggregate (mid path, round-0-proven loop + tile-local base).
__global__ __launch_bounds__(256) void agg_kernel(const float* __restrict__ feat,
                                                  const int* __restrict__ ssrc,
                                                  const int* __restrict__ offs,
                                                  const int* __restrict__ base,
                                                  float* __restrict__ out, int N) {
    const int gwave = (blockIdx.x * blockDim.x + threadIdx.x) >> 6;
    const int lane = threadIdx.x & 63;
    const int half = lane >> 5;
    const int q = lane & 31;
    const int nwaves = (gridDim.x * blockDim.x) >> 6;
    const float4* feat4 = (const float4*)feat;
    for (int v = gwave; v < N; v += nwaves) {
        const int s0 = offs[v] + base[v >> 10];
        const int s1 = offs[v + 1] + base[(v + 1) >> 10];
        float ax = 0.f, ay = 0.f, az = 0.f, aw = 0.f;
        int e = s0 + half;
        for (; e + 6 < s1; e += 8) {
            int i0 = ssrc[e], i1 = ssrc[e + 2], i2 = ssrc[e + 4], i3 = ssrc[e + 6];
            const float4 f0 = feat4[(size_t)i0 * 32 + q];
            const float4 f1 = feat4[(size_t)i1 * 32 + q];
            const float4 f2 = feat4[(size_t)i2 * 32 + q];
            const float4 f3 = feat4[(size_t)i3 * 32 + q];
            ax += (f0.x + f1.x) + (f2.x + f3.x);
            ay += (f0.y + f1.y) + (f2.y + f3.y);
            az += (f0.z + f1.z) + (f2.z + f3.z);
            aw += (f0.w + f1.w) + (f2.w + f3.w);
        }
        for (; e < s1; e += 2) {
            const float4 f0 = feat4[(size_t)ssrc[e] * 32 + q];
            ax += f0.x; ay += f0.y; az += f0.z; aw += f0.w;
        }
        ax += __shfl_xor(ax, 32);
        ay += __shfl_xor(ay, 32);
        az += __shfl_xor(az, 32);
        aw += __shfl_xor(aw, 32);
        if (half == 0) {
            float4 r;
            r.x = ax; r.y = ay; r.z = az; r.w = aw;
            ((float4*)(out + (size_t)v * F))[q] = r;
        }
    }
}

// In-place h = relu(agg @ W^T + b), reading pre-transposed wT (round-0 proven).
__global__ __launch_bounds__(256) void linear_relu_kernel(
        float* __restrict__ h, const float* __restrict__ wT,
        const float* __restrict__ b, int N) {
    __shared__ __align__(16) float sA[ROWS2][132];
    const int tid = threadIdx.x;
    const int row0 = blockIdx.x * ROWS2;

    for (int i = tid; i < ROWS2 * 32; i += 256) {
        int r = i >> 5, q = i & 31;
        int gr = row0 + r;
        float4 v = make_float4(0.f, 0.f, 0.f, 0.f);
        if (gr < N) v = ((const float4*)(h + (size_t)gr * F))[q];
        *((float4*)&sA[r][q << 2]) = v;
    }
    __syncthreads();

    const int tr = tid >> 5;
    const int tc = tid & 31;
    float acc[4][4];
#pragma unroll
    for (int i = 0; i < 4; ++i)
#pragma unroll
        for (int j = 0; j < 4; ++j) acc[i][j] = 0.f;

    const float4* wT4 = (const float4*)wT;
    for (int k = 0; k < F; k += 4) {
        const float4 w0 = wT4[(k + 0) * 32 + tc];
        const float4 w1 = wT4[(k + 1) * 32 + tc];
        const float4 w2 = wT4[(k + 2) * 32 + tc];
        const float4 w3 = wT4[(k + 3) * 32 + tc];
#pragma unroll
        for (int i = 0; i < 4; ++i) {
            const float4 a = *(const float4*)&sA[tr * 4 + i][k];
            acc[i][0] += a.x * w0.x + a.y * w1.x + a.z * w2.x + a.w * w3.x;
            acc[i][1] += a.x * w0.y + a.y * w1.y + a.z * w2.y + a.w * w3.y;
            acc[i][2] += a.x * w0.z + a.y * w1.z + a.z * w2.z + a.w * w3.z;
            acc[i][3] += a.x * w0.w + a.y * w1.w + a.z * w2.w + a.w * w3.w;
        }
    }

    const float4 bias = ((const float4*)b)[tc];
#pragma unroll
    for (int i = 0; i < 4; ++i) {
        int gr = row0 + tr * 4 + i;
        if (gr < N) {
            float4 o;
            o.x = fmaxf(acc[i][0] + bias.x, 0.f);
            o.y = fmaxf(acc[i][1] + bias.y, 0.f);
            o.z = fmaxf(acc[i][2] + bias.z, 0.f);
            o.w = fmaxf(acc[i][3] + bias.w, 0.f);
            ((float4*)(h + (size_t)gr * F))[tc] = o;
        }
    }
}

// ---------------- ws-too-small fallback path (R1-proven) ----------------
__global__ void zero_f4_kernel(float4* __restrict__ out, int n4) {
    int i = blockIdx.x * blockDim.x + threadIdx.x;
    if (i < n4) out[i] = make_float4(0.f, 0.f, 0.f, 0.f);
}

__global__ void scatter_atomic_kernel(const float* __restrict__ feat,
                                      const int* __restrict__ src,
                                      const int* __restrict__ dst,
                                      float* __restrict__ agg, int E) {
    int gid = blockIdx.x * blockDim.x + threadIdx.x;
    int e = gid >> 5;
    if (e >= E) return;
    int q = gid & 31;
    int s = src[e];
    int d = dst[e];
    const float4 v = ((const float4*)(feat + (size_t)s * F))[q];
    float* o = agg + (size_t)d * F + (q << 2);
    atomicAdd(o + 0, v.x);
    atomicAdd(o + 1, v.y);
    atomicAdd(o + 2, v.z);
    atomicAdd(o + 3, v.w);
}

__global__ __launch_bounds__(256) void linear_relu_w_kernel(
        float* __restrict__ h, const float* __restrict__ W,
        const float* __restrict__ b, int N) {
    __shared__ __align__(16) float sA[64][132];
    const int tid = threadIdx.x;
    const int row0 = blockIdx.x * 64;

    for (int i = tid; i < 64 * 32; i += 256) {
        int r = i >> 5, q = i & 31;
        int gr = row0 + r;
        float4 v = make_float4(0.f, 0.f, 0.f, 0.f);
        if (gr < N) v = ((const float4*)(h + (size_t)gr * F))[q];
        *((float4*)&sA[r][q << 2]) = v;
    }
    __syncthreads();

    const int tr = tid >> 5;
    const int tc = tid & 31;
    float acc[8][4];
#pragma unroll
    for (int i = 0; i < 8; ++i)
#pragma unroll
        for (int j = 0; j < 4; ++j) acc[i][j] = 0.f;

    const float* Wr0 = W + (size_t)(tc * 4 + 0) * F;
    const float* Wr1 = W + (size_t)(tc * 4 + 1) * F;
    const float* Wr2 = W + (size_t)(tc * 4 + 2) * F;
    const float* Wr3 = W + (size_t)(tc * 4 + 3) * F;

    for (int k = 0; k < F; k += 4) {
        const float4 w0 = *(const float4*)&Wr0[k];
        const float4 w1 = *(const float4*)&Wr1[k];
        const float4 w2 = *(const float4*)&Wr2[k];
        const float4 w3 = *(const float4*)&Wr3[k];
#pragma unroll
        for (int i = 0; i < 8; ++i) {
            const float4 a = *(const float4*)&sA[tr * 8 + i][k];
            acc[i][0] += a.x * w0.x + a.y * w0.y + a.z * w0.z + a.w * w0.w;
            acc[i][1] += a.x * w1.x + a.y * w1.y + a.z * w1.z + a.w * w1.w;
            acc[i][2] += a.x * w2.x + a.y * w2.y + a.z * w2.z + a.w * w2.w;
            acc[i][3] += a.x * w3.x + a.y * w3.y + a.z * w3.z + a.w * w3.w;
        }
    }

    const float4 bias = ((const float4*)b)[tc];
#pragma unroll
    for (int i = 0; i < 8; ++i) {
        int gr = row0 + tr * 8 + i;
        if (gr < N) {
            float4 o;
            o.x = fmaxf(acc[i][0] + bias.x, 0.f);
            o.y = fmaxf(acc[i][1] + bias.y, 0.f);
            o.z = fmaxf(acc[i][2] + bias.z, 0.f);
            o.w = fmaxf(acc[i][3] + bias.w, 0.f);
            ((float4*)(h + (size_t)gr * F))[tc] = o;
        }
    }
}

extern "C" void kernel_launch(void* const* d_in, const int* in_sizes, int n_in,
                              void* d_out, int out_size, void* d_ws, size_t ws_size,
                              hipStream_t stream) {
    const float* feat = (const float*)d_in[0];
    const int*   src  = (const int*)d_in[1];
    const int*   dst  = (const int*)d_in[2];
    const float* W    = (const float*)d_in[3];
    const float* b    = (const float*)d_in[4];
    float* out = (float*)d_out;

    const int N = in_sizes[0] / F;   // 50000
    const int E = in_sizes[1];       // 800000
    const int NB = (N + SCAN_TILE - 1) / SCAN_TILE;  // 49

    // ws layouts (4B elems):
    //  full: featH[N*64] | wT[F*F] | counts[N] | offsets[N+1] | cursor[N]
    //      | blockSums[260] | ssrc[E]
    //  mid:  (no featH) wT first.
    const size_t featH_ints = (size_t)N * 64;
    const size_t csr_ints = (size_t)(F * F) + N + (N + 1) + N + 260 + E;
    const size_t need_full = (featH_ints + csr_ints) * sizeof(int);
    const size_t need_mid  = csr_ints * sizeof(int);
    const bool nb_ok = (NB < 256) || ((N & (SCAN_TILE - 1)) != 0 && NB <= 256);

    if (ws_size >= need_full && nb_ok) {
        unsigned int* featH = (unsigned int*)d_ws;
        float* wT      = (float*)d_ws + featH_ints;
        int* counts    = (int*)wT + F * F;
        int* offsets   = counts + N;
        int* cursor    = offsets + (N + 1);
        int* blockSums = cursor + N;
        int* ssrc      = blockSums + 260;

        const int NF4 = N * 32;  // float4s in feature matrix
        prep_full_kernel<<<(NF4 + 255) / 256, 256, 0, stream>>>(feat, featH, W, wT, counts, N, NF4);
        hist_kernel<<<(E + 255) / 256, 256, 0, stream>>>(dst, counts, E);
        scan1_kernel<<<NB, 256, 0, stream>>>(counts, offsets, cursor, blockSums, N);
        scan2_kernel<<<1, 256, 0, stream>>>(blockSums, offsets, NB, N);
        place_kernel<<<(E + 255) / 256, 256, 0, stream>>>(src, dst, cursor, blockSums, ssrc, E);
        agg16_kernel<<<2048, 256, 0, stream>>>((const uint4*)featH, ssrc, offsets, blockSums, out, N);
        linear_relu_kernel<<<(N + ROWS2 - 1) / ROWS2, 256, 0, stream>>>(out, wT, b, N);
    } else if (ws_size >= need_mid && nb_ok) {
        float* wT      = (float*)d_ws;
        int* counts    = (int*)wT + F * F;
        int* offsets   = counts + N;
        int* cursor    = offsets + (N + 1);
        int* blockSums = cursor + N;
        int* ssrc      = blockSums + 260;

        prep2_kernel<<<(N + 255) / 256, 256, 0, stream>>>(W, wT, counts, N);
        hist_kernel<<<(E + 255) / 256, 256, 0, stream>>>(dst, counts, E);
        scan1_kernel<<<NB, 256, 0, stream>>>(counts, offsets, cursor, blockSums, N);
        scan2_kernel<<<1, 256, 0, stream>>>(blockSums, offsets, NB, N);
        place_kernel<<<(E + 255) / 256, 256, 0, stream>>>(src, dst, cursor, blockSums, ssrc, E);
        agg_kernel<<<2048, 256, 0, stream>>>(feat, ssrc, offsets, blockSums, out, N);
        linear_relu_kernel<<<(N + ROWS2 - 1) / ROWS2, 256, 0, stream>>>(out, wT, b, N);
    } else {
        const int n4 = N * (F / 4);
        zero_f4_kernel<<<(n4 + 255) / 256, 256, 0, stream>>>((float4*)out, n4);
        const int sthreads = E * 32;
        scatter_atomic_kernel<<<(sthreads + 255) / 256, 256, 0, stream>>>(feat, src, dst, out, E);
        linear_relu_w_kernel<<<(N + 63) / 64, 256, 0, stream>>>(out, W, b, N);
    }
}

// Round 4
// 239.530 us; speedup vs baseline: 4.0323x; 1.0254x over previous
//
#include <hip/hip_runtime.h>
#include <hip/hip_fp16.h>

#define F 128
#define TILE 256          // nodes per dst-tile (main path)
#define TSH 8             // log2(TILE)
#define CHUNK 4096        // edges per bin block
#define BCAP 8192         // LDS stage capacity (ints) in build_tile; avg tile = 4082
#define ROWS2 32
#define SCAN_TILE 1024    // mid-path (round-3 proven) tile

// ============================================================================
// prep (main path): feat fp32 -> fp16 (halves gather bandwidth) + transpose W.
// Also clears offsets[N] for the N%TILE==0 corner (last tile base covers it).
// ============================================================================
__global__ __launch_bounds__(256) void prep_full_kernel(
        const float* __restrict__ feat, unsigned int* __restrict__ featH,
        const float* __restrict__ W, float* __restrict__ wT,
        int* __restrict__ offsets, int N, int NF4) {
    int i = blockIdx.x * 256 + threadIdx.x;
    if (i < NF4) {
        const float4 v = ((const float4*)feat)[i];
        union { __half2 h; unsigned int u; } a, b;
        a.h = __floats2half2_rn(v.x, v.y);
        b.h = __floats2half2_rn(v.z, v.w);
        ((uint2*)featH)[i] = make_uint2(a.u, b.u);
    }
    if (i < F * F) {
        int o = i >> 7, k = i & 127;
        wT[k * F + o] = W[i];
    }
    if (i == 0 && (N & (TILE - 1)) == 0) offsets[N] = 0;
}

// ============================================================================
// A1: per-chunk tile histogram. Block b counts its CHUNK edges into LDS
// (LDS atomics on <=256 tile counters), writes blkCnt[t*NCHUNK+b].
// No global atomics.
// ============================================================================
__global__ __launch_bounds__(256) void binA_count_kernel(
        const int* __restrict__ dst, int* __restrict__ blkCnt,
        int E, int NT, int NCHUNK) {
    __shared__ int h[256];
    const int tid = threadIdx.x, b = blockIdx.x;
    h[tid] = 0;
    __syncthreads();
    const int e0 = b * CHUNK;
    const int n = min(CHUNK, E - e0);
    for (int i = tid; i < n; i += 256) atomicAdd(&h[dst[e0 + i] >> TSH], 1);
    __syncthreads();
    if (tid < NT) blkCnt[(size_t)tid * NCHUNK + b] = h[tid];
}

// ============================================================================
// A2: one block. Row t of blkCnt -> exclusive per-block prefix (in place) +
// tile total; block-scan totals -> bucketBase[t] (exclusive), bucketBase[NT]=E.
// Replaces scan1+scan2 over 50K with a scan over NT<=256.
// ============================================================================
__global__ __launch_bounds__(256) void binA_scan_kernel(
        int* __restrict__ blkCnt, int* __restrict__ bucketBase,
        int E, int NT, int NCHUNK) {
    __shared__ int lds[256];
    const int tid = threadIdx.x;
    int tot = 0;
    if (tid < NT) {
        int* row = blkCnt + (size_t)tid * NCHUNK;
        int s = 0;
        for (int b = 0; b < NCHUNK; ++b) {
            int v = row[b];
            row[b] = s;
            s += v;
        }
        tot = s;
    }
    lds[tid] = tot;
    __syncthreads();
    for (int off = 1; off < 256; off <<= 1) {
        int t = (tid >= off) ? lds[tid - off] : 0;
        __syncthreads();
        lds[tid] += t;
        __syncthreads();
    }
    if (tid < NT) bucketBase[tid] = lds[tid] - tot;
    if (tid == 0) bucketBase[NT] = E;
}

// ============================================================================
// A3: deterministic scatter. Block b re-reads its chunk, LDS bucket-sorts the
// (src,dst) pairs, then streams them out in contiguous per-tile runs
// (globalpos = cstart[tile] + stage_index). Coalesced writes, no global
// atomics, no cross-XCD partial-line write-backs.
// ============================================================================
__global__ __launch_bounds__(256) void binA_scatter_kernel(
        const int* __restrict__ src, const int* __restrict__ dst,
        const int* __restrict__ blkCnt, const int* __restrict__ bucketBase,
        uint2* __restrict__ edgebuf, int E, int NT, int NCHUNK) {
    __shared__ int h[256];       // hist, then staging cursor
    __shared__ int lds2[256];    // scan scratch
    __shared__ int cstart[256];  // cstart[t] = global base of this block's run - runstart
    __shared__ uint2 stage[CHUNK];
    const int tid = threadIdx.x, b = blockIdx.x;
    h[tid] = 0;
    __syncthreads();
    const int e0 = b * CHUNK;
    const int n = min(CHUNK, E - e0);
    for (int i = tid; i < n; i += 256) atomicAdd(&h[dst[e0 + i] >> TSH], 1);
    __syncthreads();
    const int myc = h[tid];
    lds2[tid] = myc;
    __syncthreads();
    for (int off = 1; off < 256; off <<= 1) {
        int t = (tid >= off) ? lds2[tid - off] : 0;
        __syncthreads();
        lds2[tid] += t;
        __syncthreads();
    }
    const int runstart = lds2[tid] - myc;  // local exclusive prefix
    if (tid < NT)
        cstart[tid] = bucketBase[tid] + blkCnt[(size_t)tid * NCHUNK + b] - runstart;
    h[tid] = runstart;   // becomes staging cursor
    __syncthreads();
    for (int i = tid; i < n; i += 256) {
        const int e = e0 + i;
        const int d = dst[e];
        const int p = atomicAdd(&h[d >> TSH], 1);
        stage[p] = make_uint2((unsigned)src[e], (unsigned)d);
    }
    __syncthreads();
    for (int i = tid; i < n; i += 256) {
        const uint2 v = stage[i];
        edgebuf[cstart[(int)v.y >> TSH] + i] = v;
    }
}

// ============================================================================
// B: per-tile CSR finalize. One block per tile: LDS hist(256) over local dst,
// LDS scan -> tile-local offsets (written to global), LDS-atomic placement of
// src into a 32KB stage, coalesced stream-out of the tile's ssrc region.
// Overflow-safe slow path (direct scatter) if a tile exceeds BCAP edges.
// ============================================================================
__global__ __launch_bounds__(256) void build_tile_kernel(
        const uint2* __restrict__ edgebuf, const int* __restrict__ bucketBase,
        int* __restrict__ offsets, int* __restrict__ ssrc, int N, int NT) {
    __shared__ int h[TILE];        // hist, then cursor
    __shared__ int excl[TILE];     // scan scratch
    __shared__ int stage[BCAP];
    const int t = blockIdx.x, tid = threadIdx.x;
    const int s0 = bucketBase[t], s1 = bucketBase[t + 1];
    const int cnt = s1 - s0;
    const int n0 = t << TSH;
    const int n1 = min(n0 + TILE, N);
    h[tid] = 0;
    __syncthreads();
    for (int i = tid; i < cnt; i += 256)
        atomicAdd(&h[(int)edgebuf[s0 + i].y & (TILE - 1)], 1);
    __syncthreads();
    const int myv = h[tid];
    excl[tid] = myv;
    __syncthreads();
    for (int off = 1; off < 256; off <<= 1) {
        int tv = (tid >= off) ? excl[tid - off] : 0;
        __syncthreads();
        excl[tid] += tv;
        __syncthreads();
    }
    const int ex = excl[tid] - myv;  // tile-local exclusive offset
    const int v = n0 + tid;
    if (v < n1) offsets[v] = ex;
    // offsets[N]: only when N is not tile-aligned (else prep wrote 0 and
    // agg uses base[NT]=E).
    if (tid == 255 && n1 == N && (N & (TILE - 1)) != 0) offsets[N] = excl[255];
    h[tid] = ex;   // becomes running cursor
    __syncthreads();
    if (cnt <= BCAP) {
        for (int i = tid; i < cnt; i += 256) {
            const uint2 e = edgebuf[s0 + i];
            const int p = atomicAdd(&h[(int)e.y & (TILE - 1)], 1);
            stage[p] = (int)e.x;
        }
        __syncthreads();
        for (int i = tid; i < cnt; i += 256) ssrc[s0 + i] = stage[i];
    } else {
        for (int i = tid; i < cnt; i += 256) {
            const uint2 e = edgebuf[s0 + i];
            const int p = atomicAdd(&h[(int)e.y & (TILE - 1)], 1);
            ssrc[s0 + p] = (int)e.x;
        }
    }
}

// ============================================================================
// fp16 gather-aggregate (round-3 proven; only base granularity changed >>TSH).
// ============================================================================
__global__ __launch_bounds__(256) void agg16_kernel(
        const uint4* __restrict__ fH,
        const int* __restrict__ ssrc,
        const int* __restrict__ offs,
        const int* __restrict__ base,
        float* __restrict__ out, int N) {
    const int gwave = (blockIdx.x * blockDim.x + threadIdx.x) >> 6;
    const int lane = threadIdx.x & 63;
    const int g = lane >> 4;
    const int q = lane & 15;
    const int nwaves = (gridDim.x * blockDim.x) >> 6;

    for (int v = gwave; v < N; v += nwaves) {
        const int s0 = offs[v] + base[v >> TSH];
        const int s1 = offs[v + 1] + base[(v + 1) >> TSH];
        float a[8];
#pragma unroll
        for (int j = 0; j < 8; ++j) a[j] = 0.f;

        int e = s0 + g;
        for (; e + 4 < s1; e += 8) {
            const int i0 = ssrc[e], i1 = ssrc[e + 4];
            const uint4 u0 = fH[(size_t)i0 * 16 + q];
            const uint4 u1 = fH[(size_t)i1 * 16 + q];
            {
                union { unsigned int u; __half2 h; } c0, c1, c2, c3;
                c0.u = u0.x; c1.u = u0.y; c2.u = u0.z; c3.u = u0.w;
                const float2 f0 = __half22float2(c0.h);
                const float2 f1 = __half22float2(c1.h);
                const float2 f2 = __half22float2(c2.h);
                const float2 f3 = __half22float2(c3.h);
                a[0] += f0.x; a[1] += f0.y; a[2] += f1.x; a[3] += f1.y;
                a[4] += f2.x; a[5] += f2.y; a[6] += f3.x; a[7] += f3.y;
            }
            {
                union { unsigned int u; __half2 h; } c0, c1, c2, c3;
                c0.u = u1.x; c1.u = u1.y; c2.u = u1.z; c3.u = u1.w;
                const float2 f0 = __half22float2(c0.h);
                const float2 f1 = __half22float2(c1.h);
                const float2 f2 = __half22float2(c2.h);
                const float2 f3 = __half22float2(c3.h);
                a[0] += f0.x; a[1] += f0.y; a[2] += f1.x; a[3] += f1.y;
                a[4] += f2.x; a[5] += f2.y; a[6] += f3.x; a[7] += f3.y;
            }
        }
        for (; e < s1; e += 4) {
            const uint4 u0 = fH[(size_t)ssrc[e] * 16 + q];
            union { unsigned int u; __half2 h; } c0, c1, c2, c3;
            c0.u = u0.x; c1.u = u0.y; c2.u = u0.z; c3.u = u0.w;
            const float2 f0 = __half22float2(c0.h);
            const float2 f1 = __half22float2(c1.h);
            const float2 f2 = __half22float2(c2.h);
            const float2 f3 = __half22float2(c3.h);
            a[0] += f0.x; a[1] += f0.y; a[2] += f1.x; a[3] += f1.y;
            a[4] += f2.x; a[5] += f2.y; a[6] += f3.x; a[7] += f3.y;
        }

#pragma unroll
        for (int j = 0; j < 8; ++j) {
            a[j] += __shfl_xor(a[j], 16);
            a[j] += __shfl_xor(a[j], 32);
        }
        if (g == 0) {
            float4* orow = (float4*)(out + (size_t)v * F);
            float4 r0, r1;
            r0.x = a[0]; r0.y = a[1]; r0.z = a[2]; r0.w = a[3];
            r1.x = a[4]; r1.y = a[5]; r1.z = a[6]; r1.w = a[7];
            orow[q * 2] = r0;
            orow[q * 2 + 1] = r1;
        }
    }
}

// In-place h = relu(agg @ W^T + b) (round-0 proven).
__global__ __launch_bounds__(256) void linear_relu_kernel(
        float* __restrict__ h, const float* __restrict__ wT,
        const float* __restrict__ b, int N) {
    __shared__ __align__(16) float sA[ROWS2][132];
    const int tid = threadIdx.x;
    const int row0 = blockIdx.x * ROWS2;

    for (int i = tid; i < ROWS2 * 32; i += 256) {
        int r = i >> 5, q = i & 31;
        int gr = row0 + r;
        float4 v = make_float4(0.f, 0.f, 0.f, 0.f);
        if (gr < N) v = ((const float4*)(h + (size_t)gr * F))[q];
        *((float4*)&sA[r][q << 2]) = v;
    }
    __syncthreads();

    const int tr = tid >> 5;
    const int tc = tid & 31;
    float acc[4][4];
#pragma unroll
    for (int i = 0; i < 4; ++i)
#pragma unroll
        for (int j = 0; j < 4; ++j) acc[i][j] = 0.f;

    const float4* wT4 = (const float4*)wT;
    for (int k = 0; k < F; k += 4) {
        const float4 w0 = wT4[(k + 0) * 32 + tc];
        const float4 w1 = wT4[(k + 1) * 32 + tc];
        const float4 w2 = wT4[(k + 2) * 32 + tc];
        const float4 w3 = wT4[(k + 3) * 32 + tc];
#pragma unroll
        for (int i = 0; i < 4; ++i) {
            const float4 a = *(const float4*)&sA[tr * 4 + i][k];
            acc[i][0] += a.x * w0.x + a.y * w1.x + a.z * w2.x + a.w * w3.x;
            acc[i][1] += a.x * w0.y + a.y * w1.y + a.z * w2.y + a.w * w3.y;
            acc[i][2] += a.x * w0.z + a.y * w1.z + a.z * w2.z + a.w * w3.z;
            acc[i][3] += a.x * w0.w + a.y * w1.w + a.z * w2.w + a.w * w3.w;
        }
    }

    const float4 bias = ((const float4*)b)[tc];
#pragma unroll
    for (int i = 0; i < 4; ++i) {
        int gr = row0 + tr * 4 + i;
        if (gr < N) {
            float4 o;
            o.x = fmaxf(acc[i][0] + bias.x, 0.f);
            o.y = fmaxf(acc[i][1] + bias.y, 0.f);
            o.z = fmaxf(acc[i][2] + bias.z, 0.f);
            o.w = fmaxf(acc[i][3] + bias.w, 0.f);
            ((float4*)(h + (size_t)gr * F))[tc] = o;
        }
    }
}

// ================= mid path (round-3 proven chain, fp32 gather) =============
__global__ void prep2_kernel(const float* __restrict__ W, float* __restrict__ wT,
                             int* __restrict__ counts, int N) {
    int i = blockIdx.x * 256 + threadIdx.x;
    if (i < F * F) {
        int o = i >> 7, k = i & 127;
        wT[k * F + o] = W[i];
    }
    if (i < N) counts[i] = 0;
}

__global__ void hist_kernel(const int* __restrict__ dst, int* __restrict__ counts, int E) {
    int e = blockIdx.x * blockDim.x + threadIdx.x;
    if (e < E) atomicAdd(&counts[dst[e]], 1);
}

__global__ __launch_bounds__(256) void scan1_kernel(const int* __restrict__ counts,
                                                    int* __restrict__ offsets,
                                                    int* __restrict__ cursor,
                                                    int* __restrict__ blockSums, int N) {
    __shared__ int lds[256];
    const int tid = threadIdx.x;
    const int i0 = blockIdx.x * SCAN_TILE + tid * 4;
    int v[4];
    int s = 0;
#pragma unroll
    for (int j = 0; j < 4; ++j) {
        int i = i0 + j;
        v[j] = (i < N) ? counts[i] : 0;
        s += v[j];
    }
    lds[tid] = s;
    __syncthreads();
    for (int off = 1; off < 256; off <<= 1) {
        int t = (tid >= off) ? lds[tid - off] : 0;
        __syncthreads();
        lds[tid] += t;
        __syncthreads();
    }
    int excl = lds[tid] - s;
#pragma unroll
    for (int j = 0; j < 4; ++j) {
        int i = i0 + j;
        if (i < N) {
            offsets[i] = excl;
            cursor[i] = excl;
        } else if (i == N) {
            offsets[N] = excl;
        }
        excl += v[j];
    }
    if (tid == 255) blockSums[blockIdx.x] = lds[255];
}

__global__ __launch_bounds__(256) void scan2_kernel(int* __restrict__ blockSums,
                                                    int* __restrict__ offsets,
                                                    int NB, int N) {
    __shared__ int lds[256];
    const int tid = threadIdx.x;
    int s = (tid < NB) ? blockSums[tid] : 0;
    lds[tid] = s;
    __syncthreads();
    for (int off = 1; off < 256; off <<= 1) {
        int t = (tid >= off) ? lds[tid - off] : 0;
        __syncthreads();
        lds[tid] += t;
        __syncthreads();
    }
    if (tid < NB) blockSums[tid] = lds[tid] - s;
    if (tid == NB && NB < 256) blockSums[NB] = lds[255];
    if (tid == 0 && (N & (SCAN_TILE - 1)) == 0) offsets[N] = 0;
}

__global__ void place_kernel(const int* __restrict__ src, const int* __restrict__ dst,
                             int* __restrict__ cursor, const int* __restrict__ base,
                             int* __restrict__ ssrc, int E) {
    int e = blockIdx.x * blockDim.x + threadIdx.x;
    if (e < E) {
        int d = dst[e];
        int pos = atomicAdd(&cursor[d], 1) + base[d >> 10];
        ssrc[pos] = src[e];
    }
}

__global__ __launch_bounds__(256) void agg_kernel(const float* __restrict__ feat,
                                                  const int* __restrict__ ssrc,
                                                  const int* __restrict__ offs,
                                                  const int* __restrict__ base,
                                                  float* __restrict__ out, int N) {
    const int gwave = (blockIdx.x * blockDim.x + threadIdx.x) >> 6;
    const int lane = threadIdx.x & 63;
    const int half = lane >> 5;
    const int q = lane & 31;
    const int nwaves = (gridDim.x * blockDim.x) >> 6;
    const float4* feat4 = (const float4*)feat;
    for (int v = gwave; v < N; v += nwaves) {
        const int s0 = offs[v] + base[v >> 10];
        const int s1 = offs[v + 1] + base[(v + 1) >> 10];
        float ax = 0.f, ay = 0.f, az = 0.f, aw = 0.f;
        int e = s0 + half;
        for (; e + 6 < s1; e += 8) {
            int i0 = ssrc[e], i1 = ssrc[e + 2], i2 = ssrc[e + 4], i3 = ssrc[e + 6];
            const float4 f0 = feat4[(size_t)i0 * 32 + q];
            const float4 f1 = feat4[(size_t)i1 * 32 + q];
            const float4 f2 = feat4[(size_t)i2 * 32 + q];
            const float4 f3 = feat4[(size_t)i3 * 32 + q];
            ax += (f0.x + f1.x) + (f2.x + f3.x);
            ay += (f0.y + f1.y) + (f2.y + f3.y);
            az += (f0.z + f1.z) + (f2.z + f3.z);
            aw += (f0.w + f1.w) + (f2.w + f3.w);
        }
        for (; e < s1; e += 2) {
            const float4 f0 = feat4[(size_t)ssrc[e] * 32 + q];
            ax += f0.x; ay += f0.y; az += f0.z; aw += f0.w;
        }
        ax += __shfl_xor(ax, 32);
        ay += __shfl_xor(ay, 32);
        az += __shfl_xor(az, 32);
        aw += __shfl_xor(aw, 32);
        if (half == 0) {
            float4 r;
            r.x = ax; r.y = ay; r.z = az; r.w = aw;
            ((float4*)(out + (size_t)v * F))[q] = r;
        }
    }
}

// ---------------- ws-too-small fallback path (R1-proven) ----------------
__global__ void zero_f4_kernel(float4* __restrict__ out, int n4) {
    int i = blockIdx.x * blockDim.x + threadIdx.x;
    if (i < n4) out[i] = make_float4(0.f, 0.f, 0.f, 0.f);
}

__global__ void scatter_atomic_kernel(const float* __restrict__ feat,
                                      const int* __restrict__ src,
                                      const int* __restrict__ dst,
                                      float* __restrict__ agg, int E) {
    int gid = blockIdx.x * blockDim.x + threadIdx.x;
    int e = gid >> 5;
    if (e >= E) return;
    int q = gid & 31;
    int s = src[e];
    int d = dst[e];
    const float4 v = ((const float4*)(feat + (size_t)s * F))[q];
    float* o = agg + (size_t)d * F + (q << 2);
    atomicAdd(o + 0, v.x);
    atomicAdd(o + 1, v.y);
    atomicAdd(o + 2, v.z);
    atomicAdd(o + 3, v.w);
}

__global__ __launch_bounds__(256) void linear_relu_w_kernel(
        float* __restrict__ h, const float* __restrict__ W,
        const float* __restrict__ b, int N) {
    __shared__ __align__(16) float sA[64][132];
    const int tid = threadIdx.x;
    const int row0 = blockIdx.x * 64;

    for (int i = tid; i < 64 * 32; i += 256) {
        int r = i >> 5, q = i & 31;
        int gr = row0 + r;
        float4 v = make_float4(0.f, 0.f, 0.f, 0.f);
        if (gr < N) v = ((const float4*)(h + (size_t)gr * F))[q];
        *((float4*)&sA[r][q << 2]) = v;
    }
    __syncthreads();

    const int tr = tid >> 5;
    const int tc = tid & 31;
    float acc[8][4];
#pragma unroll
    for (int i = 0; i < 8; ++i)
#pragma unroll
        for (int j = 0; j < 4; ++j) acc[i][j] = 0.f;

    const float* Wr0 = W + (size_t)(tc * 4 + 0) * F;
    const float* Wr1 = W + (size_t)(tc * 4 + 1) * F;
    const float* Wr2 = W + (size_t)(tc * 4 + 2) * F;
    const float* Wr3 = W + (size_t)(tc * 4 + 3) * F;

    for (int k = 0; k < F; k += 4) {
        const float4 w0 = *(const float4*)&Wr0[k];
        const float4 w1 = *(const float4*)&Wr1[k];
        const float4 w2 = *(const float4*)&Wr2[k];
        const float4 w3 = *(const float4*)&Wr3[k];
#pragma unroll
        for (int i = 0; i < 8; ++i) {
            const float4 a = *(const float4*)&sA[tr * 8 + i][k];
            acc[i][0] += a.x * w0.x + a.y * w0.y + a.z * w0.z + a.w * w0.w;
            acc[i][1] += a.x * w1.x + a.y * w1.y + a.z * w1.z + a.w * w1.w;
            acc[i][2] += a.x * w2.x + a.y * w2.y + a.z * w2.z + a.w * w2.w;
            acc[i][3] += a.x * w3.x + a.y * w3.y + a.z * w3.z + a.w * w3.w;
        }
    }

    const float4 bias = ((const float4*)b)[tc];
#pragma unroll
    for (int i = 0; i < 8; ++i) {
        int gr = row0 + tr * 8 + i;
        if (gr < N) {
            float4 o;
            o.x = fmaxf(acc[i][0] + bias.x, 0.f);
            o.y = fmaxf(acc[i][1] + bias.y, 0.f);
            o.z = fmaxf(acc[i][2] + bias.z, 0.f);
            o.w = fmaxf(acc[i][3] + bias.w, 0.f);
            ((float4*)(h + (size_t)gr * F))[tc] = o;
        }
    }
}

extern "C" void kernel_launch(void* const* d_in, const int* in_sizes, int n_in,
                              void* d_out, int out_size, void* d_ws, size_t ws_size,
                              hipStream_t stream) {
    const float* feat = (const float*)d_in[0];
    const int*   src  = (const int*)d_in[1];
    const int*   dst  = (const int*)d_in[2];
    const float* W    = (const float*)d_in[3];
    const float* b    = (const float*)d_in[4];
    float* out = (float*)d_out;

    const int N = in_sizes[0] / F;   // 50000
    const int E = in_sizes[1];       // 800000
    const int NT = (N + TILE - 1) / TILE;          // 196
    const int NCHUNK = (E + CHUNK - 1) / CHUNK;    // 196
    const int NB = (N + SCAN_TILE - 1) / SCAN_TILE;

    auto align4 = [](size_t x) { return (x + 3) & ~(size_t)3; };

    // main-path ws layout (4B units, each region 16B aligned):
    // featH[N*64] | wT[F*F] | offsets[N+1] | bucketBase[NT+1] | blkCnt[NT*NCHUNK]
    // | edgebuf[2E] | ssrc[E]
    const size_t o_featH = 0;
    const size_t o_wT    = align4(o_featH + (size_t)N * 64);
    const size_t o_offs  = align4(o_wT + (size_t)F * F);
    const size_t o_bb    = align4(o_offs + (size_t)N + 1);
    const size_t o_blk   = align4(o_bb + (size_t)NT + 1);
    const size_t o_ebuf  = align4(o_blk + (size_t)NT * NCHUNK);
    const size_t o_ssrc  = align4(o_ebuf + (size_t)2 * E);
    const size_t need_main = (o_ssrc + (size_t)E) * sizeof(int);

    // mid-path (round-3) layout
    const size_t csr_ints = (size_t)(F * F) + N + (N + 1) + N + 260 + E;
    const size_t need_mid = csr_ints * sizeof(int);
    const bool nb_ok = (NB < 256) || ((N & (SCAN_TILE - 1)) != 0 && NB <= 256);

    if (ws_size >= need_main && NT <= 256) {
        unsigned int* featH = (unsigned int*)d_ws;
        float* wT        = (float*)d_ws + o_wT;
        int* offsets     = (int*)d_ws + o_offs;
        int* bucketBase  = (int*)d_ws + o_bb;
        int* blkCnt      = (int*)d_ws + o_blk;
        uint2* edgebuf   = (uint2*)((int*)d_ws + o_ebuf);
        int* ssrc        = (int*)d_ws + o_ssrc;

        const int NF4 = N * 32;
        prep_full_kernel<<<(NF4 + 255) / 256, 256, 0, stream>>>(feat, featH, W, wT, offsets, N, NF4);
        binA_count_kernel<<<NCHUNK, 256, 0, stream>>>(dst, blkCnt, E, NT, NCHUNK);
        binA_scan_kernel<<<1, 256, 0, stream>>>(blkCnt, bucketBase, E, NT, NCHUNK);
        binA_scatter_kernel<<<NCHUNK, 256, 0, stream>>>(src, dst, blkCnt, bucketBase, edgebuf, E, NT, NCHUNK);
        build_tile_kernel<<<NT, 256, 0, stream>>>(edgebuf, bucketBase, offsets, ssrc, N, NT);
        agg16_kernel<<<2048, 256, 0, stream>>>((const uint4*)featH, ssrc, offsets, bucketBase, out, N);
        linear_relu_kernel<<<(N + ROWS2 - 1) / ROWS2, 256, 0, stream>>>(out, wT, b, N);
    } else if (ws_size >= need_mid && nb_ok) {
        float* wT      = (float*)d_ws;
        int* counts    = (int*)wT + F * F;
        int* offsets   = counts + N;
        int* cursor    = offsets + (N + 1);
        int* blockSums = cursor + N;
        int* ssrc      = blockSums + 260;

        prep2_kernel<<<(N + 255) / 256, 256, 0, stream>>>(W, wT, counts, N);
        hist_kernel<<<(E + 255) / 256, 256, 0, stream>>>(dst, counts, E);
        scan1_kernel<<<NB, 256, 0, stream>>>(counts, offsets, cursor, blockSums, N);
        scan2_kernel<<<1, 256, 0, stream>>>(blockSums, offsets, NB, N);
        place_kernel<<<(E + 255) / 256, 256, 0, stream>>>(src, dst, cursor, blockSums, ssrc, E);
        agg_kernel<<<2048, 256, 0, stream>>>(feat, ssrc, offsets, blockSums, out, N);
        linear_relu_kernel<<<(N + ROWS2 - 1) / ROWS2, 256, 0, stream>>>(out, wT, b, N);
    } else {
        const int n4 = N * (F / 4);
        zero_f4_kernel<<<(n4 + 255) / 256, 256, 0, stream>>>((float4*)out, n4);
        const int sthreads = E * 32;
        scatter_atomic_kernel<<<(sthreads + 255) / 256, 256, 0, stream>>>(feat, src, dst, out, E);
        linear_relu_w_kernel<<<(N + 63) / 64, 256, 0, stream>>>(out, W, b, N);
    }
}

// Round 5
// 202.023 us; speedup vs baseline: 4.7809x; 1.1857x over previous
//
#include <hip/hip_runtime.h>
#include <hip/hip_fp16.h>

#define F 128
#define TILE 256          // nodes per dst-tile (main path)
#define TSH 8             // log2(TILE)
#define CHUNK 4096        // edges per bin block
#define BCAP 8192         // LDS stage capacity (ints) in build_tile; avg tile = 4082
#define ROWS2 32
#define SCAN_TILE 1024    // mid-path (round-3 proven) tile

// ============================================================================
// prep (main path): feat fp32 -> fp16 (halves gather bandwidth) + transpose W.
// Also clears offsets[N] for the N%TILE==0 corner (last tile base covers it).
// ============================================================================
__global__ __launch_bounds__(256) void prep_full_kernel(
        const float* __restrict__ feat, unsigned int* __restrict__ featH,
        const float* __restrict__ W, float* __restrict__ wT,
        int* __restrict__ offsets, int N, int NF4) {
    int i = blockIdx.x * 256 + threadIdx.x;
    if (i < NF4) {
        const float4 v = ((const float4*)feat)[i];
        union { __half2 h; unsigned int u; } a, b;
        a.h = __floats2half2_rn(v.x, v.y);
        b.h = __floats2half2_rn(v.z, v.w);
        ((uint2*)featH)[i] = make_uint2(a.u, b.u);
    }
    if (i < F * F) {
        int o = i >> 7, k = i & 127;
        wT[k * F + o] = W[i];
    }
    if (i == 0 && (N & (TILE - 1)) == 0) offsets[N] = 0;
}

// ============================================================================
// A1: per-chunk tile histogram. Block b counts its CHUNK edges into LDS
// (LDS atomics on <=256 tile counters), writes blkCnt[t*NCHUNK+b].
// No global atomics.
// ============================================================================
__global__ __launch_bounds__(256) void binA_count_kernel(
        const int* __restrict__ dst, int* __restrict__ blkCnt,
        int E, int NT, int NCHUNK) {
    __shared__ int h[256];
    const int tid = threadIdx.x, b = blockIdx.x;
    h[tid] = 0;
    __syncthreads();
    const int e0 = b * CHUNK;
    const int n = min(CHUNK, E - e0);
    for (int i = tid; i < n; i += 256) atomicAdd(&h[dst[e0 + i] >> TSH], 1);
    __syncthreads();
    if (tid < NT) blkCnt[(size_t)tid * NCHUNK + b] = h[tid];
}

// ============================================================================
// A2 (parallelized; round-4's single-block version was 59us @ 0.04% occupancy):
// one block per tile row t.
//  (a) bucketBase[t] = sum of all rows < t  (256-thread strided reduce over the
//      L2-resident 150KB table; redundant across blocks but fully parallel)
//  (b) block scan of row t -> blkOff[t][b] = bucketBase[t] + excl-prefix
// blkCnt is read-only; no cross-block dependency.
// ============================================================================
__global__ __launch_bounds__(256) void binA_scan_kernel(
        const int* __restrict__ blkCnt, int* __restrict__ blkOff,
        int* __restrict__ bucketBase, int E, int NT, int NCHUNK) {
    __shared__ int red[256];
    const int t = blockIdx.x;
    const int tid = threadIdx.x;

    // (a) base = sum over blkCnt[0 .. t*NCHUNK)
    const int lim = t * NCHUNK;
    int s = 0;
    for (int i = tid; i < lim; i += 256) s += blkCnt[i];
    red[tid] = s;
    __syncthreads();
    for (int off = 128; off > 0; off >>= 1) {
        if (tid < off) red[tid] += red[tid + off];
        __syncthreads();
    }
    const int base = red[0];
    __syncthreads();

    // (b) scan row t with carry, 256 elems at a time
    int carry = base;
    for (int c0 = 0; c0 < NCHUNK; c0 += 256) {
        const int b = c0 + tid;
        const int v = (b < NCHUNK) ? blkCnt[(size_t)t * NCHUNK + b] : 0;
        red[tid] = v;
        __syncthreads();
        for (int off = 1; off < 256; off <<= 1) {
            int tv = (tid >= off) ? red[tid - off] : 0;
            __syncthreads();
            red[tid] += tv;
            __syncthreads();
        }
        const int excl = red[tid] - v;
        if (b < NCHUNK) blkOff[(size_t)t * NCHUNK + b] = carry + excl;
        const int tot = red[255];
        __syncthreads();
        carry += tot;
    }
    if (tid == 0) {
        bucketBase[t] = base;
        if (t == 0) bucketBase[NT] = E;
    }
}

// ============================================================================
// A3: deterministic scatter. Block b re-reads its chunk, LDS bucket-sorts the
// (src,dst) pairs, then streams them out in contiguous per-tile runs, PACKED
// as (src<<8)|(dst&255) — halves edgebuf traffic (gated on N < 2^24).
// Coalesced writes, no global atomics.
// ============================================================================
__global__ __launch_bounds__(256) void binA_scatter_kernel(
        const int* __restrict__ src, const int* __restrict__ dst,
        const int* __restrict__ blkOff,
        unsigned int* __restrict__ edgebuf, int E, int NT, int NCHUNK) {
    __shared__ int h[256];       // hist, then staging cursor
    __shared__ int lds2[256];    // scan scratch
    __shared__ int cstart[256];  // global base of this block's per-tile run - runstart
    __shared__ uint2 stage[CHUNK];
    const int tid = threadIdx.x, b = blockIdx.x;
    h[tid] = 0;
    __syncthreads();
    const int e0 = b * CHUNK;
    const int n = min(CHUNK, E - e0);
    for (int i = tid; i < n; i += 256) atomicAdd(&h[dst[e0 + i] >> TSH], 1);
    __syncthreads();
    const int myc = h[tid];
    lds2[tid] = myc;
    __syncthreads();
    for (int off = 1; off < 256; off <<= 1) {
        int t = (tid >= off) ? lds2[tid - off] : 0;
        __syncthreads();
        lds2[tid] += t;
        __syncthreads();
    }
    const int runstart = lds2[tid] - myc;  // local exclusive prefix
    if (tid < NT) cstart[tid] = blkOff[(size_t)tid * NCHUNK + b] - runstart;
    h[tid] = runstart;   // becomes staging cursor
    __syncthreads();
    for (int i = tid; i < n; i += 256) {
        const int e = e0 + i;
        const int d = dst[e];
        const int p = atomicAdd(&h[d >> TSH], 1);
        stage[p] = make_uint2((unsigned)src[e], (unsigned)d);
    }
    __syncthreads();
    for (int i = tid; i < n; i += 256) {
        const uint2 v = stage[i];
        const int t = (int)v.y >> TSH;
        edgebuf[cstart[t] + i] = (v.x << 8) | (v.y & 255u);
    }
}

// ============================================================================
// B: per-tile CSR finalize. One block per tile: LDS hist(256) over local dst,
// LDS scan -> tile-local offsets, LDS-atomic placement of src into a 32KB
// stage, coalesced stream-out. Overflow-safe slow path if tile > BCAP edges.
// ============================================================================
__global__ __launch_bounds__(256) void build_tile_kernel(
        const unsigned int* __restrict__ edgebuf, const int* __restrict__ bucketBase,
        int* __restrict__ offsets, int* __restrict__ ssrc, int N, int NT) {
    __shared__ int h[TILE];        // hist, then cursor
    __shared__ int excl[TILE];     // scan scratch
    __shared__ int stage[BCAP];
    const int t = blockIdx.x, tid = threadIdx.x;
    const int s0 = bucketBase[t], s1 = bucketBase[t + 1];
    const int cnt = s1 - s0;
    const int n0 = t << TSH;
    const int n1 = min(n0 + TILE, N);
    h[tid] = 0;
    __syncthreads();
    for (int i = tid; i < cnt; i += 256)
        atomicAdd(&h[(int)(edgebuf[s0 + i] & 255u)], 1);
    __syncthreads();
    const int myv = h[tid];
    excl[tid] = myv;
    __syncthreads();
    for (int off = 1; off < 256; off <<= 1) {
        int tv = (tid >= off) ? excl[tid - off] : 0;
        __syncthreads();
        excl[tid] += tv;
        __syncthreads();
    }
    const int ex = excl[tid] - myv;  // tile-local exclusive offset
    const int v = n0 + tid;
    if (v < n1) offsets[v] = ex;
    if (tid == 255 && n1 == N && (N & (TILE - 1)) != 0) offsets[N] = excl[255];
    h[tid] = ex;   // becomes running cursor
    __syncthreads();
    if (cnt <= BCAP) {
        for (int i = tid; i < cnt; i += 256) {
            const unsigned int e = edgebuf[s0 + i];
            const int p = atomicAdd(&h[(int)(e & 255u)], 1);
            stage[p] = (int)(e >> 8);
        }
        __syncthreads();
        for (int i = tid; i < cnt; i += 256) ssrc[s0 + i] = stage[i];
    } else {
        for (int i = tid; i < cnt; i += 256) {
            const unsigned int e = edgebuf[s0 + i];
            const int p = atomicAdd(&h[(int)(e & 255u)], 1);
            ssrc[s0 + p] = (int)(e >> 8);
        }
    }
}

// ============================================================================
// fp16 gather-aggregate (round-3/4 proven).
// ============================================================================
__global__ __launch_bounds__(256) void agg16_kernel(
        const uint4* __restrict__ fH,
        const int* __restrict__ ssrc,
        const int* __restrict__ offs,
        const int* __restrict__ base,
        float* __restrict__ out, int N) {
    const int gwave = (blockIdx.x * blockDim.x + threadIdx.x) >> 6;
    const int lane = threadIdx.x & 63;
    const int g = lane >> 4;
    const int q = lane & 15;
    const int nwaves = (gridDim.x * blockDim.x) >> 6;

    for (int v = gwave; v < N; v += nwaves) {
        const int s0 = offs[v] + base[v >> TSH];
        const int s1 = offs[v + 1] + base[(v + 1) >> TSH];
        float a[8];
#pragma unroll
        for (int j = 0; j < 8; ++j) a[j] = 0.f;

        int e = s0 + g;
        for (; e + 4 < s1; e += 8) {
            const int i0 = ssrc[e], i1 = ssrc[e + 4];
            const uint4 u0 = fH[(size_t)i0 * 16 + q];
            const uint4 u1 = fH[(size_t)i1 * 16 + q];
            {
                union { unsigned int u; __half2 h; } c0, c1, c2, c3;
                c0.u = u0.x; c1.u = u0.y; c2.u = u0.z; c3.u = u0.w;
                const float2 f0 = __half22float2(c0.h);
                const float2 f1 = __half22float2(c1.h);
                const float2 f2 = __half22float2(c2.h);
                const float2 f3 = __half22float2(c3.h);
                a[0] += f0.x; a[1] += f0.y; a[2] += f1.x; a[3] += f1.y;
                a[4] += f2.x; a[5] += f2.y; a[6] += f3.x; a[7] += f3.y;
            }
            {
                union { unsigned int u; __half2 h; } c0, c1, c2, c3;
                c0.u = u1.x; c1.u = u1.y; c2.u = u1.z; c3.u = u1.w;
                const float2 f0 = __half22float2(c0.h);
                const float2 f1 = __half22float2(c1.h);
                const float2 f2 = __half22float2(c2.h);
                const float2 f3 = __half22float2(c3.h);
                a[0] += f0.x; a[1] += f0.y; a[2] += f1.x; a[3] += f1.y;
                a[4] += f2.x; a[5] += f2.y; a[6] += f3.x; a[7] += f3.y;
            }
        }
        for (; e < s1; e += 4) {
            const uint4 u0 = fH[(size_t)ssrc[e] * 16 + q];
            union { unsigned int u; __half2 h; } c0, c1, c2, c3;
            c0.u = u0.x; c1.u = u0.y; c2.u = u0.z; c3.u = u0.w;
            const float2 f0 = __half22float2(c0.h);
            const float2 f1 = __half22float2(c1.h);
            const float2 f2 = __half22float2(c2.h);
            const float2 f3 = __half22float2(c3.h);
            a[0] += f0.x; a[1] += f0.y; a[2] += f1.x; a[3] += f1.y;
            a[4] += f2.x; a[5] += f2.y; a[6] += f3.x; a[7] += f3.y;
        }

#pragma unroll
        for (int j = 0; j < 8; ++j) {
            a[j] += __shfl_xor(a[j], 16);
            a[j] += __shfl_xor(a[j], 32);
        }
        if (g == 0) {
            float4* orow = (float4*)(out + (size_t)v * F);
            float4 r0, r1;
            r0.x = a[0]; r0.y = a[1]; r0.z = a[2]; r0.w = a[3];
            r1.x = a[4]; r1.y = a[5]; r1.z = a[6]; r1.w = a[7];
            orow[q * 2] = r0;
            orow[q * 2 + 1] = r1;
        }
    }
}

// In-place h = relu(agg @ W^T + b) (round-0 proven).
__global__ __launch_bounds__(256) void linear_relu_kernel(
        float* __restrict__ h, const float* __restrict__ wT,
        const float* __restrict__ b, int N) {
    __shared__ __align__(16) float sA[ROWS2][132];
    const int tid = threadIdx.x;
    const int row0 = blockIdx.x * ROWS2;

    for (int i = tid; i < ROWS2 * 32; i += 256) {
        int r = i >> 5, q = i & 31;
        int gr = row0 + r;
        float4 v = make_float4(0.f, 0.f, 0.f, 0.f);
        if (gr < N) v = ((const float4*)(h + (size_t)gr * F))[q];
        *((float4*)&sA[r][q << 2]) = v;
    }
    __syncthreads();

    const int tr = tid >> 5;
    const int tc = tid & 31;
    float acc[4][4];
#pragma unroll
    for (int i = 0; i < 4; ++i)
#pragma unroll
        for (int j = 0; j < 4; ++j) acc[i][j] = 0.f;

    const float4* wT4 = (const float4*)wT;
    for (int k = 0; k < F; k += 4) {
        const float4 w0 = wT4[(k + 0) * 32 + tc];
        const float4 w1 = wT4[(k + 1) * 32 + tc];
        const float4 w2 = wT4[(k + 2) * 32 + tc];
        const float4 w3 = wT4[(k + 3) * 32 + tc];
#pragma unroll
        for (int i = 0; i < 4; ++i) {
            const float4 a = *(const float4*)&sA[tr * 4 + i][k];
            acc[i][0] += a.x * w0.x + a.y * w1.x + a.z * w2.x + a.w * w3.x;
            acc[i][1] += a.x * w0.y + a.y * w1.y + a.z * w2.y + a.w * w3.y;
            acc[i][2] += a.x * w0.z + a.y * w1.z + a.z * w2.z + a.w * w3.z;
            acc[i][3] += a.x * w0.w + a.y * w1.w + a.z * w2.w + a.w * w3.w;
        }
    }

    const float4 bias = ((const float4*)b)[tc];
#pragma unroll
    for (int i = 0; i < 4; ++i) {
        int gr = row0 + tr * 4 + i;
        if (gr < N) {
            float4 o;
            o.x = fmaxf(acc[i][0] + bias.x, 0.f);
            o.y = fmaxf(acc[i][1] + bias.y, 0.f);
            o.z = fmaxf(acc[i][2] + bias.z, 0.f);
            o.w = fmaxf(acc[i][3] + bias.w, 0.f);
            ((float4*)(h + (size_t)gr * F))[tc] = o;
        }
    }
}

// ================= mid path (round-3 proven chain, fp32 gather) =============
__global__ void prep2_kernel(const float* __restrict__ W, float* __restrict__ wT,
                             int* __restrict__ counts, int N) {
    int i = blockIdx.x * 256 + threadIdx.x;
    if (i < F * F) {
        int o = i >> 7, k = i & 127;
        wT[k * F + o] = W[i];
    }
    if (i < N) counts[i] = 0;
}

__global__ void hist_kernel(const int* __restrict__ dst, int* __restrict__ counts, int E) {
    int e = blockIdx.x * blockDim.x + threadIdx.x;
    if (e < E) atomicAdd(&counts[dst[e]], 1);
}

__global__ __launch_bounds__(256) void scan1_kernel(const int* __restrict__ counts,
                                                    int* __restrict__ offsets,
                                                    int* __restrict__ cursor,
                                                    int* __restrict__ blockSums, int N) {
    __shared__ int lds[256];
    const int tid = threadIdx.x;
    const int i0 = blockIdx.x * SCAN_TILE + tid * 4;
    int v[4];
    int s = 0;
#pragma unroll
    for (int j = 0; j < 4; ++j) {
        int i = i0 + j;
        v[j] = (i < N) ? counts[i] : 0;
        s += v[j];
    }
    lds[tid] = s;
    __syncthreads();
    for (int off = 1; off < 256; off <<= 1) {
        int t = (tid >= off) ? lds[tid - off] : 0;
        __syncthreads();
        lds[tid] += t;
        __syncthreads();
    }
    int excl = lds[tid] - s;
#pragma unroll
    for (int j = 0; j < 4; ++j) {
        int i = i0 + j;
        if (i < N) {
            offsets[i] = excl;
            cursor[i] = excl;
        } else if (i == N) {
            offsets[N] = excl;
        }
        excl += v[j];
    }
    if (tid == 255) blockSums[blockIdx.x] = lds[255];
}

__global__ __launch_bounds__(256) void scan2_kernel(int* __restrict__ blockSums,
                                                    int* __restrict__ offsets,
                                                    int NB, int N) {
    __shared__ int lds[256];
    const int tid = threadIdx.x;
    int s = (tid < NB) ? blockSums[tid] : 0;
    lds[tid] = s;
    __syncthreads();
    for (int off = 1; off < 256; off <<= 1) {
        int t = (tid >= off) ? lds[tid - off] : 0;
        __syncthreads();
        lds[tid] += t;
        __syncthreads();
    }
    if (tid < NB) blockSums[tid] = lds[tid] - s;
    if (tid == NB && NB < 256) blockSums[NB] = lds[255];
    if (tid == 0 && (N & (SCAN_TILE - 1)) == 0) offsets[N] = 0;
}

__global__ void place_kernel(const int* __restrict__ src, const int* __restrict__ dst,
                             int* __restrict__ cursor, const int* __restrict__ base,
                             int* __restrict__ ssrc, int E) {
    int e = blockIdx.x * blockDim.x + threadIdx.x;
    if (e < E) {
        int d = dst[e];
        int pos = atomicAdd(&cursor[d], 1) + base[d >> 10];
        ssrc[pos] = src[e];
    }
}

__global__ __launch_bounds__(256) void agg_kernel(const float* __restrict__ feat,
                                                  const int* __restrict__ ssrc,
                                                  const int* __restrict__ offs,
                                                  const int* __restrict__ base,
                                                  float* __restrict__ out, int N) {
    const int gwave = (blockIdx.x * blockDim.x + threadIdx.x) >> 6;
    const int lane = threadIdx.x & 63;
    const int half = lane >> 5;
    const int q = lane & 31;
    const int nwaves = (gridDim.x * blockDim.x) >> 6;
    const float4* feat4 = (const float4*)feat;
    for (int v = gwave; v < N; v += nwaves) {
        const int s0 = offs[v] + base[v >> 10];
        const int s1 = offs[v + 1] + base[(v + 1) >> 10];
        float ax = 0.f, ay = 0.f, az = 0.f, aw = 0.f;
        int e = s0 + half;
        for (; e + 6 < s1; e += 8) {
            int i0 = ssrc[e], i1 = ssrc[e + 2], i2 = ssrc[e + 4], i3 = ssrc[e + 6];
            const float4 f0 = feat4[(size_t)i0 * 32 + q];
            const float4 f1 = feat4[(size_t)i1 * 32 + q];
            const float4 f2 = feat4[(size_t)i2 * 32 + q];
            const float4 f3 = feat4[(size_t)i3 * 32 + q];
            ax += (f0.x + f1.x) + (f2.x + f3.x);
            ay += (f0.y + f1.y) + (f2.y + f3.y);
            az += (f0.z + f1.z) + (f2.z + f3.z);
            aw += (f0.w + f1.w) + (f2.w + f3.w);
        }
        for (; e < s1; e += 2) {
            const float4 f0 = feat4[(size_t)ssrc[e] * 32 + q];
            ax += f0.x; ay += f0.y; az += f0.z; aw += f0.w;
        }
        ax += __shfl_xor(ax, 32);
        ay += __shfl_xor(ay, 32);
        az += __shfl_xor(az, 32);
        aw += __shfl_xor(aw, 32);
        if (half == 0) {
            float4 r;
            r.x = ax; r.y = ay; r.z = az; r.w = aw;
            ((float4*)(out + (size_t)v * F))[q] = r;
        }
    }
}

// ---------------- ws-too-small fallback path (R1-proven) ----------------
__global__ void zero_f4_kernel(float4* __restrict__ out, int n4) {
    int i = blockIdx.x * blockDim.x + threadIdx.x;
    if (i < n4) out[i] = make_float4(0.f, 0.f, 0.f, 0.f);
}

__global__ void scatter_atomic_kernel(const float* __restrict__ feat,
                                      const int* __restrict__ src,
                                      const int* __restrict__ dst,
                                      float* __restrict__ agg, int E) {
    int gid = blockIdx.x * blockDim.x + threadIdx.x;
    int e = gid >> 5;
    if (e >= E) return;
    int q = gid & 31;
    int s = src[e];
    int d = dst[e];
    const float4 v = ((const float4*)(feat + (size_t)s * F))[q];
    float* o = agg + (size_t)d * F + (q << 2);
    atomicAdd(o + 0, v.x);
    atomicAdd(o + 1, v.y);
    atomicAdd(o + 2, v.z);
    atomicAdd(o + 3, v.w);
}

__global__ __launch_bounds__(256) void linear_relu_w_kernel(
        float* __restrict__ h, const float* __restrict__ W,
        const float* __restrict__ b, int N) {
    __shared__ __align__(16) float sA[64][132];
    const int tid = threadIdx.x;
    const int row0 = blockIdx.x * 64;

    for (int i = tid; i < 64 * 32; i += 256) {
        int r = i >> 5, q = i & 31;
        int gr = row0 + r;
        float4 v = make_float4(0.f, 0.f, 0.f, 0.f);
        if (gr < N) v = ((const float4*)(h + (size_t)gr * F))[q];
        *((float4*)&sA[r][q << 2]) = v;
    }
    __syncthreads();

    const int tr = tid >> 5;
    const int tc = tid & 31;
    float acc[8][4];
#pragma unroll
    for (int i = 0; i < 8; ++i)
#pragma unroll
        for (int j = 0; j < 4; ++j) acc[i][j] = 0.f;

    const float* Wr0 = W + (size_t)(tc * 4 + 0) * F;
    const float* Wr1 = W + (size_t)(tc * 4 + 1) * F;
    const float* Wr2 = W + (size_t)(tc * 4 + 2) * F;
    const float* Wr3 = W + (size_t)(tc * 4 + 3) * F;

    for (int k = 0; k < F; k += 4) {
        const float4 w0 = *(const float4*)&Wr0[k];
        const float4 w1 = *(const float4*)&Wr1[k];
        const float4 w2 = *(const float4*)&Wr2[k];
        const float4 w3 = *(const float4*)&Wr3[k];
#pragma unroll
        for (int i = 0; i < 8; ++i) {
            const float4 a = *(const float4*)&sA[tr * 8 + i][k];
            acc[i][0] += a.x * w0.x + a.y * w0.y + a.z * w0.z + a.w * w0.w;
            acc[i][1] += a.x * w1.x + a.y * w1.y + a.z * w1.z + a.w * w1.w;
            acc[i][2] += a.x * w2.x + a.y * w2.y + a.z * w2.z + a.w * w2.w;
            acc[i][3] += a.x * w3.x + a.y * w3.y + a.z * w3.z + a.w * w3.w;
        }
    }

    const float4 bias = ((const float4*)b)[tc];
#pragma unroll
    for (int i = 0; i < 8; ++i) {
        int gr = row0 + tr * 8 + i;
        if (gr < N) {
            float4 o;
            o.x = fmaxf(acc[i][0] + bias.x, 0.f);
            o.y = fmaxf(acc[i][1] + bias.y, 0.f);
            o.z = fmaxf(acc[i][2] + bias.z, 0.f);
            o.w = fmaxf(acc[i][3] + bias.w, 0.f);
            ((float4*)(h + (size_t)gr * F))[tc] = o;
        }
    }
}

extern "C" void kernel_launch(void* const* d_in, const int* in_sizes, int n_in,
                              void* d_out, int out_size, void* d_ws, size_t ws_size,
                              hipStream_t stream) {
    const float* feat = (const float*)d_in[0];
    const int*   src  = (const int*)d_in[1];
    const int*   dst  = (const int*)d_in[2];
    const float* W    = (const float*)d_in[3];
    const float* b    = (const float*)d_in[4];
    float* out = (float*)d_out;

    const int N = in_sizes[0] / F;   // 50000
    const int E = in_sizes[1];       // 800000
    const int NT = (N + TILE - 1) / TILE;          // 196
    const int NCHUNK = (E + CHUNK - 1) / CHUNK;    // 196
    const int NB = (N + SCAN_TILE - 1) / SCAN_TILE;

    auto align4 = [](size_t x) { return (x + 3) & ~(size_t)3; };

    // main-path ws layout (4B units, each region 16B aligned):
    // featH[N*64] | wT[F*F] | offsets[N+1] | bucketBase[NT+1] | blkCnt[NT*NCHUNK]
    // | blkOff[NT*NCHUNK] | edgebuf[E] | ssrc[E]
    const size_t o_featH = 0;
    const size_t o_wT    = align4(o_featH + (size_t)N * 64);
    const size_t o_offs  = align4(o_wT + (size_t)F * F);
    const size_t o_bb    = align4(o_offs + (size_t)N + 1);
    const size_t o_blk   = align4(o_bb + (size_t)NT + 1);
    const size_t o_boff  = align4(o_blk + (size_t)NT * NCHUNK);
    const size_t o_ebuf  = align4(o_boff + (size_t)NT * NCHUNK);
    const size_t o_ssrc  = align4(o_ebuf + (size_t)E);
    const size_t need_main = (o_ssrc + (size_t)E) * sizeof(int);

    // mid-path (round-3) layout
    const size_t csr_ints = (size_t)(F * F) + N + (N + 1) + N + 260 + E;
    const size_t need_mid = csr_ints * sizeof(int);
    const bool nb_ok = (NB < 256) || ((N & (SCAN_TILE - 1)) != 0 && NB <= 256);

    if (ws_size >= need_main && NT <= 256 && N < (1 << 24)) {
        unsigned int* featH = (unsigned int*)d_ws;
        float* wT            = (float*)d_ws + o_wT;
        int* offsets         = (int*)d_ws + o_offs;
        int* bucketBase      = (int*)d_ws + o_bb;
        int* blkCnt          = (int*)d_ws + o_blk;
        int* blkOff          = (int*)d_ws + o_boff;
        unsigned int* edgebuf = (unsigned int*)((int*)d_ws + o_ebuf);
        int* ssrc            = (int*)d_ws + o_ssrc;

        const int NF4 = N * 32;
        prep_full_kernel<<<(NF4 + 255) / 256, 256, 0, stream>>>(feat, featH, W, wT, offsets, N, NF4);
        binA_count_kernel<<<NCHUNK, 256, 0, stream>>>(dst, blkCnt, E, NT, NCHUNK);
        binA_scan_kernel<<<NT, 256, 0, stream>>>(blkCnt, blkOff, bucketBase, E, NT, NCHUNK);
        binA_scatter_kernel<<<NCHUNK, 256, 0, stream>>>(src, dst, blkOff, edgebuf, E, NT, NCHUNK);
        build_tile_kernel<<<NT, 256, 0, stream>>>(edgebuf, bucketBase, offsets, ssrc, N, NT);
        agg16_kernel<<<2048, 256, 0, stream>>>((const uint4*)featH, ssrc, offsets, bucketBase, out, N);
        linear_relu_kernel<<<(N + ROWS2 - 1) / ROWS2, 256, 0, stream>>>(out, wT, b, N);
    } else if (ws_size >= need_mid && nb_ok) {
        float* wT      = (float*)d_ws;
        int* counts    = (int*)wT + F * F;
        int* offsets   = counts + N;
        int* cursor    = offsets + (N + 1);
        int* blockSums = cursor + N;
        int* ssrc      = blockSums + 260;

        prep2_kernel<<<(N + 255) / 256, 256, 0, stream>>>(W, wT, counts, N);
        hist_kernel<<<(E + 255) / 256, 256, 0, stream>>>(dst, counts, E);
        scan1_kernel<<<NB, 256, 0, stream>>>(counts, offsets, cursor, blockSums, N);
        scan2_kernel<<<1, 256, 0, stream>>>(blockSums, offsets, NB, N);
        place_kernel<<<(E + 255) / 256, 256, 0, stream>>>(src, dst, cursor, blockSums, ssrc, E);
        agg_kernel<<<2048, 256, 0, stream>>>(feat, ssrc, offsets, blockSums, out, N);
        linear_relu_kernel<<<(N + ROWS2 - 1) / ROWS2, 256, 0, stream>>>(out, wT, b, N);
    } else {
        const int n4 = N * (F / 4);
        zero_f4_kernel<<<(n4 + 255) / 256, 256, 0, stream>>>((float4*)out, n4);
        const int sthreads = E * 32;
        scatter_atomic_kernel<<<(sthreads + 255) / 256, 256, 0, stream>>>(feat, src, dst, out, E);
        linear_relu_w_kernel<<<(N + 63) / 64, 256, 0, stream>>>(out, W, b, N);
    }
}